// Round 3
// baseline (146.130 us; speedup 1.0000x reference)
//
#include <hip/hip_runtime.h>
#include <hip/hip_bf16.h>

// CapsuleLayer routing, bf16 MFMA, 6 dispatches.
// B=512,P=1152,N=10,T=16,D=8, 3 iters. Verified 16x16x32 bf16 layouts:
//   A: m=lane&15, k=q*8+j   B: n=lane&15, k=q*8+j   D: col=lane&15, row=q*4+r
// r16 changes vs r15 (r15 traffic cut -18.6us CONFIRMED ~11TB/s effective
// L2/L3 serving; continue cutting traffic):
//  - k_sv: 2x2 output tile (2 mblk x 2 n per block), grid (16,5)x1024thr,
//    4 acc streams. Traffic 9.44*Ng + 2.95*Mg: (32,5)141.6 -> (16,5)94.4MB.
//    Same 18-kc-per-wave split, same 16-partial sum order: bit-identical.
//  - k_ga: 4 pdblk per block, grid 144x1024thr. All 4 quarters read the same
//    Vt frags (L1 reuse): Vt traffic 46->23MB/dispatch. bred 126KB LDS (ok,
//    gfx950 workgroup LDS max 160KB; 8-phase GEMM template uses 128KB).
// Chain prep -> sv0 -> ga0 -> sv1 -> ga1 -> sv2 is structurally minimal:
// r11 proved grid-wide sync costs 4x; r14 proved TLP/LDS-pad neutral.

typedef __attribute__((ext_vector_type(8))) short bfrag;   // 8 bf16
typedef __attribute__((ext_vector_type(4))) float f32x4;

constexpr int B_ = 512, P_ = 1152, N_ = 10, NT_ = 160;
constexpr int K1_ = 9216, NKC_ = 288;

__device__ __forceinline__ unsigned short f2bf(float f) {
    unsigned u = __float_as_uint(f);
    return (unsigned short)((u + 0x7fffu + ((u >> 16) & 1u)) >> 16);  // RNE
}
__device__ __forceinline__ float bf2f(unsigned short s) {
    return __uint_as_float((unsigned)s << 16);
}
__device__ __forceinline__ bfrag mkfrag(f32x4 a, f32x4 b, float c) {
    bfrag f;
    f[0] = (short)f2bf(a.x * c); f[1] = (short)f2bf(a.y * c);
    f[2] = (short)f2bf(a.z * c); f[3] = (short)f2bf(a.w * c);
    f[4] = (short)f2bf(b.x * c); f[5] = (short)f2bf(b.y * c);
    f[6] = (short)f2bf(b.z * c); f[7] = (short)f2bf(b.w * c);
    return f;
}

// Xb:  [mblk 32][kc 288][lane 64][8]  elem = x[mblk*16+col][kc*32+q*8+j]
// Xga: [pdblk 576][kc 16][lane 64][8] elem = x[kc*32+q*8+j][pdblk*16+col]
// Wc:  [n 10][kc 288][lane 64][8]     elem = c[p,n]*W[p][n*16+col][j], p=kc*4+q
// Wb:  [pdblk 576][lane 64][40]       elem(mt*4+r) = W[p][mt*16+q*4+r][d]
// Vt:  [kc 16][mt 10][lane 64][8]     elem = v[kc*32+q*8+j][mt*16+col]  (bf16)
__global__ __launch_bounds__(256) void k_prep(const float* __restrict__ x,
                                              const float* __restrict__ W,
                                              unsigned short* __restrict__ Xb,
                                              unsigned short* __restrict__ Xga,
                                              unsigned short* __restrict__ Wc,
                                              unsigned short* __restrict__ Wb) {
    const int bid = blockIdx.x, tid = threadIdx.x;
    const int w = tid >> 6, ln = tid & 63, col = ln & 15, q = ln >> 4;
    if (bid < 1152) {          // x transpose tile -> Xga AND Xb fragments
        __shared__ unsigned short tile[64][72];   // [pd_local][b_local]
        const int pd0 = (bid >> 3) * 64, b0 = (bid & 7) * 64;
        const int c0 = tid & 63, r0 = tid >> 6;
#pragma unroll
        for (int i = 0; i < 16; ++i) {
            const int br = i * 4 + r0;   // coalesced: 64 lanes x 4B contiguous
            tile[c0][br] = f2bf(x[(size_t)(b0 + br) * K1_ + pd0 + c0]);
        }
        __syncthreads();
        // Xga: 8 frags (pdblk_l 0..3, kc_l 0..1); wave w does f=w, f=w+4
#pragma unroll
        for (int fi = 0; fi < 2; ++fi) {
            const int f = w + fi * 4;
            const int pdblk_l = f & 3, kc_l = f >> 2;
            bfrag fr;
#pragma unroll
            for (int j = 0; j < 8; ++j)
                fr[j] = (short)tile[pdblk_l * 16 + col][kc_l * 32 + q * 8 + j];
            const size_t addr = ((size_t)(((pd0 >> 4) + pdblk_l) * 16 + (b0 >> 5) + kc_l)) * 512 + ln * 8;
            *(bfrag*)(Xga + addr) = fr;   // 1KB/wave contiguous
        }
        // Xb: 8 frags (mblk_l 0..3, kc_l 0..1); wave w does f=w, f=w+4
#pragma unroll
        for (int fi = 0; fi < 2; ++fi) {
            const int f = w + fi * 4;
            const int mblk_l = f & 3, kc_l = f >> 2;
            bfrag fr;
#pragma unroll
            for (int j = 0; j < 8; ++j)
                fr[j] = (short)tile[kc_l * 32 + q * 8 + j][mblk_l * 16 + col];
            const size_t addr = ((size_t)(((b0 >> 4) + mblk_l) * NKC_ + (pd0 >> 5) + kc_l)) * 512 + ln * 8;
            *(bfrag*)(Xb + addr) = fr;    // 1KB/wave contiguous
        }
    } else if (bid < 1872) {   // Wc0 = bf16(0.1*W): one wave per (n,kc)
        const int task = (bid - 1152) * 4 + w;     // < 2880 = 10*288
        const int n = task / NKC_, kc = task % NKC_;
        const int p = kc * 4 + q;
        const float* wr = W + ((size_t)p * NT_ + n * 16 + col) * 8;
        const bfrag f = mkfrag(*(const f32x4*)wr, *(const f32x4*)(wr + 4), 0.1f);
        *(bfrag*)(Wc + ((size_t)(n * NKC_ + kc)) * 512 + ln * 8) = f;  // 1KB/wave
    } else {                   // Wb: contraction-layout bf16 W
        const int idx = (bid - 1872) * 256 + tid;   // < 36864
        const int p = ((idx >> 6) * 16 + (idx & 15)) >> 3, d = idx & 7;
        const int q2 = (idx & 63) >> 4;
        unsigned short* dst = Wb + (size_t)idx * 40;
#pragma unroll
        for (int mt = 0; mt < N_; ++mt)
#pragma unroll
            for (int r = 0; r < 4; ++r)
                dst[mt * 4 + r] = f2bf(W[((size_t)p * NT_ + mt * 16 + q2 * 4 + r) * 8 + d]);
    }
}

// ---- GEMM1 + squash. grid (16,5), 1024 thr; 2 mblk x 2 n per block ------
// 4 acc streams: each Xb frag feeds 2 MFMAs, each Wc frag feeds 2 MFMAs.
__global__ __launch_bounds__(1024) void k_sv(const unsigned short* __restrict__ Xb,
                                             const unsigned short* __restrict__ Wc,
                                             unsigned short* __restrict__ Vt,
                                             float* __restrict__ outp,
                                             int final_it) {
    __shared__ float red[16][4][256];   // 64KB: 16 waves x 4 streams
    const int tid = threadIdx.x;
    const int w = tid >> 6, lane = tid & 63, col = lane & 15, q = lane >> 4;
    const int bx = blockIdx.x;          // mblks 2bx, 2bx+1
    const int n0 = blockIdx.y * 2;      // n's n0, n0+1

    f32x4 acc00 = (f32x4){0.f, 0.f, 0.f, 0.f};
    f32x4 acc01 = (f32x4){0.f, 0.f, 0.f, 0.f};
    f32x4 acc10 = (f32x4){0.f, 0.f, 0.f, 0.f};
    f32x4 acc11 = (f32x4){0.f, 0.f, 0.f, 0.f};
    const int kc0 = w * 18;             // 18 chunks per wave
    const unsigned short* X0 = Xb + ((size_t)((2 * bx) * NKC_ + kc0)) * 512 + lane * 8;
    const unsigned short* X1 = X0 + (size_t)NKC_ * 512;
    const unsigned short* W0 = Wc + ((size_t)(n0 * NKC_ + kc0)) * 512 + lane * 8;
    const unsigned short* W1 = W0 + (size_t)NKC_ * 512;
#pragma unroll 3
    for (int i = 0; i < 18; ++i) {
        const bfrag a0 = *(const bfrag*)X0;
        const bfrag a1 = *(const bfrag*)X1;
        const bfrag b0 = *(const bfrag*)W0;
        const bfrag b1 = *(const bfrag*)W1;
        acc00 = __builtin_amdgcn_mfma_f32_16x16x32_bf16(a0, b0, acc00, 0, 0, 0);
        acc01 = __builtin_amdgcn_mfma_f32_16x16x32_bf16(a0, b1, acc01, 0, 0, 0);
        acc10 = __builtin_amdgcn_mfma_f32_16x16x32_bf16(a1, b0, acc10, 0, 0, 0);
        acc11 = __builtin_amdgcn_mfma_f32_16x16x32_bf16(a1, b1, acc11, 0, 0, 0);
        X0 += 512; X1 += 512; W0 += 512; W1 += 512;
    }
#pragma unroll
    for (int r = 0; r < 4; ++r) {
        const int li = r * 64 + q * 16 + col;
        red[w][0][li] = acc00[r];
        red[w][1][li] = acc01[r];
        red[w][2][li] = acc10[r];
        red[w][3][li] = acc11[r];
    }
    __syncthreads();
    if (w < 4) {                        // stream w: mi = w>>1, ni = w&1
        const int mi = w >> 1, ni = w & 1;
        const int mt = n0 + ni;
#pragma unroll
        for (int r = 0; r < 4; ++r) {
            const int li = r * 64 + q * 16 + col;
            float s = 0.f;
#pragma unroll
            for (int j = 0; j < 16; ++j) s += red[j][w][li];
            float sq = s * s;                      // t = col (16 lanes)
            sq += __shfl_xor(sq, 1);
            sq += __shfl_xor(sq, 2);
            sq += __shfl_xor(sq, 4);
            sq += __shfl_xor(sq, 8);
            const float norm = sqrtf(sq);
            const float scale = sq / (1.0f + sq * (norm + 1e-9f));
            const float vv = s * scale;
            const int b = (2 * bx + mi) * 16 + q * 4 + r;   // b>>5 == bx
            if (final_it) {
                outp[(size_t)b * NT_ + mt * 16 + col] = vv;
            } else {
                const int b5 = b & 31;             // fragment layout write
                Vt[((size_t)(bx * N_ + mt)) * 512
                   + ((b5 >> 3) * 16 + col) * 8 + (b5 & 7)] = f2bf(vv);
            }
        }
    }
}

// ---- GEMM2 + contraction + softmax + Wc rebuild. grid 144, 1024 thr ------
// Four pdblk per block; all quarters read the same Vt frags -> L1 reuse.
__global__ __launch_bounds__(1024) void k_ga(const unsigned short* __restrict__ Vt,
                                             const unsigned short* __restrict__ Xga,
                                             const unsigned short* __restrict__ Wb,
                                             const float* __restrict__ W,
                                             float* __restrict__ bbar,
                                             unsigned short* __restrict__ Wc,
                                             int accum) {
    __shared__ float bred[4][3][64][41];   // 126KB; stride 41: conflict-free
    __shared__ float csm[8][N_];
    const int tid = threadIdx.x;
    const int w = tid >> 6, lane = tid & 63, col = lane & 15, q = lane >> 4;
    const int qt = w >> 2, wl = w & 3;
    const int pdblk = blockIdx.x * 4 + qt;
    const int p = (pdblk * 16 + col) >> 3, d = col & 7;

    f32x4 acc[N_];
#pragma unroll
    for (int mt = 0; mt < N_; ++mt) acc[mt] = (f32x4){0.f, 0.f, 0.f, 0.f};

    const int kb0 = wl * 4;
#pragma unroll
    for (int kc = kb0; kc < kb0 + 4; ++kc) {
        const bfrag bf = *(const bfrag*)(Xga + ((size_t)(pdblk * 16 + kc)) * 512 + lane * 8);
#pragma unroll
        for (int mt = 0; mt < N_; ++mt) {
            const bfrag af = *(const bfrag*)(Vt + ((size_t)(kc * N_ + mt)) * 512 + lane * 8);
            acc[mt] = __builtin_amdgcn_mfma_f32_16x16x32_bf16(af, bf, acc[mt], 0, 0, 0);
        }
    }
    if (wl) {
#pragma unroll
        for (int mt = 0; mt < N_; ++mt)
#pragma unroll
            for (int r = 0; r < 4; ++r)
                bred[qt][wl - 1][lane][mt * 4 + r] = acc[mt][r];
    }
    __syncthreads();
    if (wl == 0) {
        unsigned short wv[40];
        const unsigned short* ws2 = Wb + ((size_t)(pdblk * 64 + lane)) * 40;
#pragma unroll
        for (int v = 0; v < 40; ++v) wv[v] = ws2[v];
        float part[N_];
#pragma unroll
        for (int mt = 0; mt < N_; ++mt) {
            float s = 0.f;
#pragma unroll
            for (int r = 0; r < 4; ++r) {
                const float h = acc[mt][r] + bred[qt][0][lane][mt * 4 + r]
                              + bred[qt][1][lane][mt * 4 + r]
                              + bred[qt][2][lane][mt * 4 + r];
                s = fmaf(bf2f(wv[mt * 4 + r]), h, s);
            }
            s += __shfl_xor(s, 1);    // reduce over d
            s += __shfl_xor(s, 2);
            s += __shfl_xor(s, 4);
            s += __shfl_xor(s, 16);   // reduce over t-quarters
            s += __shfl_xor(s, 32);
            part[mt] = s;
        }
        if (q == 0 && d == 0) {       // lanes 0 and 8: this quarter's 2 p's
            const int pl = col >> 3;
            float bv[N_];
#pragma unroll
            for (int mt = 0; mt < N_; ++mt) {
                bv[mt] = part[mt] * (1.0f / 512.0f);
                if (accum) bv[mt] += bbar[(size_t)p * N_ + mt];
                bbar[(size_t)p * N_ + mt] = bv[mt];
            }
            float m = -1e30f;
#pragma unroll
            for (int mt = 0; mt < N_; ++mt) m = fmaxf(m, bv[mt]);
            float sum = 0.f;
#pragma unroll
            for (int mt = 0; mt < N_; ++mt) { bv[mt] = __expf(bv[mt] - m); sum += bv[mt]; }
            const float inv = 1.f / sum;
#pragma unroll
            for (int mt = 0; mt < N_; ++mt) csm[qt * 2 + pl][mt] = bv[mt] * inv;
        }
    }
    __syncthreads();
    const int p0 = blockIdx.x * 8;
#pragma unroll
    for (int task = tid; task < 1280; task += 1024) {   // Wc rebuild (8 p's)
        const int pl = task / 160, rem = task % 160;
        const int n = rem >> 4, cl = rem & 15;
        const int pp = p0 + pl;
        const float c = csm[pl][n];
        const float* wr = W + ((size_t)pp * NT_ + n * 16 + cl) * 8;
        const size_t addr = ((size_t)(n * NKC_ + (pp >> 2))) * 512 + (pp & 3) * 128 + cl * 8;
        *(bfrag*)(Wc + addr) = mkfrag(*(const f32x4*)wr, *(const f32x4*)(wr + 4), c);
    }
}

extern "C" void kernel_launch(void* const* d_in, const int* in_sizes, int n_in,
                              void* d_out, int out_size, void* d_ws, size_t ws_size,
                              hipStream_t stream) {
    const float* x = (const float*)d_in[0];   // fp32 [B][P*D]
    const float* W = (const float*)d_in[1];   // fp32 [P][NT][D]

    char* wsp = (char*)d_ws;
    float* bbar = (float*)wsp;                                      // 46080 B
    unsigned short* Xb  = (unsigned short*)(wsp + 46080);           // 9.44 MB
    unsigned short* Xga = Xb + (size_t)32 * NKC_ * 512;             // 9.44 MB
    unsigned short* Wc  = Xga + (size_t)576 * 16 * 512;             // 2.95 MB
    unsigned short* Wb  = Wc + (size_t)N_ * NKC_ * 512;             // 2.95 MB
    unsigned short* Vt  = Wb + (size_t)576 * 64 * 40;               // 160 KB
    float* outp = (float*)d_out;

    k_prep<<<dim3(2016), dim3(256), 0, stream>>>(x, W, Xb, Xga, Wc, Wb);
    k_sv<<<dim3(16, 5), dim3(1024), 0, stream>>>(Xb, Wc, Vt, outp, 0);
    k_ga<<<dim3(144), dim3(1024), 0, stream>>>(Vt, Xga, Wb, W, bbar, Wc, 0);
    k_sv<<<dim3(16, 5), dim3(1024), 0, stream>>>(Xb, Wc, Vt, outp, 0);
    k_ga<<<dim3(144), dim3(1024), 0, stream>>>(Vt, Xga, Wb, W, bbar, Wc, 1);
    k_sv<<<dim3(16, 5), dim3(1024), 0, stream>>>(Xb, Wc, Vt, outp, 1);
}

// Round 4
// 137.886 us; speedup vs baseline: 1.0598x; 1.0598x over previous
//
#include <hip/hip_runtime.h>
#include <hip/hip_bf16.h>

// CapsuleLayer routing, bf16 MFMA, 6 dispatches.
// B=512,P=1152,N=10,T=16,D=8, 3 iters. Verified 16x16x32 bf16 layouts:
//   A: m=lane&15, k=q*8+j   B: n=lane&15, k=q*8+j   D: col=lane&15, row=q*4+r
// r17 = r15 (136.1us, proven) + XCD-aware block swizzle in k_sv ONLY.
// r16 post-mortem: cutting traffic by halving grid (160->80, 288->144 blocks)
// REGRESSED +10us -- the ~12TB/s effective fabric rate needs CU coverage.
// r17 keeps r15's grids and instead co-locates Wc-sharing blocks per XCD:
//   L = (wg&7)*20 + (wg>>3): each n-group's 32 blocks span <=2 XCDs, so the
//   576KB Wc slice is pulled from L3 ~1-2x per group instead of 8x scattered
//   (~94MB -> ~6MB cross-die traffic per k_sv dispatch; Wc is dirty in the
//   k_ga writers' L2s before sv1/sv2, so these are true fabric transfers).
// Pure block relabeling: bit-identical output vs r15.
// Chain prep -> sv0 -> ga0 -> sv1 -> ga1 -> sv2 is structurally minimal:
// r11 proved grid-wide sync costs 4x; r14 proved TLP/LDS-pad neutral.

typedef __attribute__((ext_vector_type(8))) short bfrag;   // 8 bf16
typedef __attribute__((ext_vector_type(4))) float f32x4;

constexpr int B_ = 512, P_ = 1152, N_ = 10, NT_ = 160;
constexpr int K1_ = 9216, NKC_ = 288;

__device__ __forceinline__ unsigned short f2bf(float f) {
    unsigned u = __float_as_uint(f);
    return (unsigned short)((u + 0x7fffu + ((u >> 16) & 1u)) >> 16);  // RNE
}
__device__ __forceinline__ float bf2f(unsigned short s) {
    return __uint_as_float((unsigned)s << 16);
}
__device__ __forceinline__ bfrag mkfrag(f32x4 a, f32x4 b, float c) {
    bfrag f;
    f[0] = (short)f2bf(a.x * c); f[1] = (short)f2bf(a.y * c);
    f[2] = (short)f2bf(a.z * c); f[3] = (short)f2bf(a.w * c);
    f[4] = (short)f2bf(b.x * c); f[5] = (short)f2bf(b.y * c);
    f[6] = (short)f2bf(b.z * c); f[7] = (short)f2bf(b.w * c);
    return f;
}

// Xb:  [mblk 32][kc 288][lane 64][8]  elem = x[mblk*16+col][kc*32+q*8+j]
// Xga: [pdblk 576][kc 16][lane 64][8] elem = x[kc*32+q*8+j][pdblk*16+col]
// Wc:  [n 10][kc 288][lane 64][8]     elem = c[p,n]*W[p][n*16+col][j], p=kc*4+q
// Wb:  [pdblk 576][lane 64][40]       elem(mt*4+r) = W[p][mt*16+q*4+r][d]
// Vt:  [kc 16][mt 10][lane 64][8]     elem = v[kc*32+q*8+j][mt*16+col]  (bf16)
__global__ __launch_bounds__(256) void k_prep(const float* __restrict__ x,
                                              const float* __restrict__ W,
                                              unsigned short* __restrict__ Xb,
                                              unsigned short* __restrict__ Xga,
                                              unsigned short* __restrict__ Wc,
                                              unsigned short* __restrict__ Wb) {
    const int bid = blockIdx.x, tid = threadIdx.x;
    const int w = tid >> 6, ln = tid & 63, col = ln & 15, q = ln >> 4;
    if (bid < 1152) {          // x transpose tile -> Xga AND Xb fragments
        __shared__ unsigned short tile[64][72];   // [pd_local][b_local]
        const int pd0 = (bid >> 3) * 64, b0 = (bid & 7) * 64;
        const int c0 = tid & 63, r0 = tid >> 6;
#pragma unroll
        for (int i = 0; i < 16; ++i) {
            const int br = i * 4 + r0;   // coalesced: 64 lanes x 4B contiguous
            tile[c0][br] = f2bf(x[(size_t)(b0 + br) * K1_ + pd0 + c0]);
        }
        __syncthreads();
        // Xga: 8 frags (pdblk_l 0..3, kc_l 0..1); wave w does f=w, f=w+4
#pragma unroll
        for (int fi = 0; fi < 2; ++fi) {
            const int f = w + fi * 4;
            const int pdblk_l = f & 3, kc_l = f >> 2;
            bfrag fr;
#pragma unroll
            for (int j = 0; j < 8; ++j)
                fr[j] = (short)tile[pdblk_l * 16 + col][kc_l * 32 + q * 8 + j];
            const size_t addr = ((size_t)(((pd0 >> 4) + pdblk_l) * 16 + (b0 >> 5) + kc_l)) * 512 + ln * 8;
            *(bfrag*)(Xga + addr) = fr;   // 1KB/wave contiguous
        }
        // Xb: 8 frags (mblk_l 0..3, kc_l 0..1); wave w does f=w, f=w+4
#pragma unroll
        for (int fi = 0; fi < 2; ++fi) {
            const int f = w + fi * 4;
            const int mblk_l = f & 3, kc_l = f >> 2;
            bfrag fr;
#pragma unroll
            for (int j = 0; j < 8; ++j)
                fr[j] = (short)tile[kc_l * 32 + q * 8 + j][mblk_l * 16 + col];
            const size_t addr = ((size_t)(((b0 >> 4) + mblk_l) * NKC_ + (pd0 >> 5) + kc_l)) * 512 + ln * 8;
            *(bfrag*)(Xb + addr) = fr;    // 1KB/wave contiguous
        }
    } else if (bid < 1872) {   // Wc0 = bf16(0.1*W): one wave per (n,kc)
        const int task = (bid - 1152) * 4 + w;     // < 2880 = 10*288
        const int n = task / NKC_, kc = task % NKC_;
        const int p = kc * 4 + q;
        const float* wr = W + ((size_t)p * NT_ + n * 16 + col) * 8;
        const bfrag f = mkfrag(*(const f32x4*)wr, *(const f32x4*)(wr + 4), 0.1f);
        *(bfrag*)(Wc + ((size_t)(n * NKC_ + kc)) * 512 + ln * 8) = f;  // 1KB/wave
    } else {                   // Wb: contraction-layout bf16 W
        const int idx = (bid - 1872) * 256 + tid;   // < 36864
        const int p = ((idx >> 6) * 16 + (idx & 15)) >> 3, d = idx & 7;
        const int q2 = (idx & 63) >> 4;
        unsigned short* dst = Wb + (size_t)idx * 40;
#pragma unroll
        for (int mt = 0; mt < N_; ++mt)
#pragma unroll
            for (int r = 0; r < 4; ++r)
                dst[mt * 4 + r] = f2bf(W[((size_t)p * NT_ + mt * 16 + q2 * 4 + r) * 8 + d]);
    }
}

// ---- GEMM1 + squash. grid (32,5), 1024 thr = 16 waves, 2 n's per block ----
// XCD swizzle: wg%8 is the XCD (round-robin dispatch); L=(wg&7)*20+(wg>>3)
// clusters each n-group (shared 576KB Wc slice) onto <=2 XCDs.
__global__ __launch_bounds__(1024) void k_sv(const unsigned short* __restrict__ Xb,
                                             const unsigned short* __restrict__ Wc,
                                             unsigned short* __restrict__ Vt,
                                             float* __restrict__ outp,
                                             int final_it) {
    __shared__ float red[16][2][256];   // 32KB: all 16 waves x {n0,n1}
    const int tid = threadIdx.x;
    const int w = tid >> 6, lane = tid & 63, col = lane & 15, q = lane >> 4;
    const int wg = blockIdx.x + blockIdx.y * 32;   // hw dispatch index (x-major)
    const int L  = (wg & 7) * 20 + (wg >> 3);      // bijection on [0,160)
    const int mblk = L & 31;            // 16 b-rows
    const int n0 = (L >> 5) * 2;        // two n per block

    f32x4 accA = (f32x4){0.f, 0.f, 0.f, 0.f};
    f32x4 accB = (f32x4){0.f, 0.f, 0.f, 0.f};
    const int kc0 = w * 18;             // 18 chunks per wave
    const unsigned short* Xp = Xb + ((size_t)(mblk * NKC_ + kc0)) * 512 + lane * 8;
    const unsigned short* W0 = Wc + ((size_t)(n0 * NKC_ + kc0)) * 512 + lane * 8;
    const unsigned short* W1 = W0 + (size_t)NKC_ * 512;
#pragma unroll 3
    for (int i = 0; i < 18; ++i) {
        const bfrag a  = *(const bfrag*)Xp;
        const bfrag b0 = *(const bfrag*)W0;
        const bfrag b1 = *(const bfrag*)W1;
        accA = __builtin_amdgcn_mfma_f32_16x16x32_bf16(a, b0, accA, 0, 0, 0);
        accB = __builtin_amdgcn_mfma_f32_16x16x32_bf16(a, b1, accB, 0, 0, 0);
        Xp += 512; W0 += 512; W1 += 512;
    }
#pragma unroll
    for (int r = 0; r < 4; ++r) {
        red[w][0][r * 64 + q * 16 + col] = accA[r];
        red[w][1][r * 64 + q * 16 + col] = accB[r];
    }
    __syncthreads();
    if (w < 2) {                        // wave 0 -> n0, wave 1 -> n0+1
        const int mt = n0 + w;
#pragma unroll
        for (int r = 0; r < 4; ++r) {
            const int li = r * 64 + q * 16 + col;
            float s = 0.f;
#pragma unroll
            for (int j = 0; j < 16; ++j) s += red[j][w][li];
            float sq = s * s;                      // t = col (16 lanes)
            sq += __shfl_xor(sq, 1);
            sq += __shfl_xor(sq, 2);
            sq += __shfl_xor(sq, 4);
            sq += __shfl_xor(sq, 8);
            const float norm = sqrtf(sq);
            const float scale = sq / (1.0f + sq * (norm + 1e-9f));
            const float vv = s * scale;
            const int b = mblk * 16 + q * 4 + r;
            if (final_it) {
                outp[(size_t)b * NT_ + mt * 16 + col] = vv;
            } else {
                const int b5 = b & 31;             // fragment layout write
                Vt[((size_t)((mblk >> 1) * N_ + mt)) * 512
                   + ((b5 >> 3) * 16 + col) * 8 + (b5 & 7)] = f2bf(vv);
            }
        }
    }
}

// ---- GEMM2 + contraction + softmax + Wc rebuild. grid 288, 512 thr -------
// Two pdblk per block (halves share Vt frags -> L1 reuse halves Vt traffic).
__global__ __launch_bounds__(512) void k_ga(const unsigned short* __restrict__ Vt,
                                            const unsigned short* __restrict__ Xga,
                                            const unsigned short* __restrict__ Wb,
                                            const float* __restrict__ W,
                                            float* __restrict__ bbar,
                                            unsigned short* __restrict__ Wc,
                                            int accum) {
    __shared__ float bred[2][3][64][41];   // per half: 3 storing waves
    __shared__ float csm[4][N_];
    const int tid = threadIdx.x;
    const int w = tid >> 6, lane = tid & 63, col = lane & 15, q = lane >> 4;
    const int half = w >> 2, wl = w & 3;
    const int pdblk = blockIdx.x * 2 + half;
    const int p = (pdblk * 16 + col) >> 3, d = col & 7;

    f32x4 acc[N_];
#pragma unroll
    for (int mt = 0; mt < N_; ++mt) acc[mt] = (f32x4){0.f, 0.f, 0.f, 0.f};

    const int kb0 = wl * 4;
#pragma unroll
    for (int kc = kb0; kc < kb0 + 4; ++kc) {
        const bfrag bf = *(const bfrag*)(Xga + ((size_t)(pdblk * 16 + kc)) * 512 + lane * 8);
#pragma unroll
        for (int mt = 0; mt < N_; ++mt) {
            const bfrag af = *(const bfrag*)(Vt + ((size_t)(kc * N_ + mt)) * 512 + lane * 8);
            acc[mt] = __builtin_amdgcn_mfma_f32_16x16x32_bf16(af, bf, acc[mt], 0, 0, 0);
        }
    }
    if (wl) {
#pragma unroll
        for (int mt = 0; mt < N_; ++mt)
#pragma unroll
            for (int r = 0; r < 4; ++r)
                bred[half][wl - 1][lane][mt * 4 + r] = acc[mt][r];
    }
    __syncthreads();
    if (wl == 0) {
        unsigned short wv[40];
        const unsigned short* ws2 = Wb + ((size_t)(pdblk * 64 + lane)) * 40;
#pragma unroll
        for (int v = 0; v < 40; ++v) wv[v] = ws2[v];
        float part[N_];
#pragma unroll
        for (int mt = 0; mt < N_; ++mt) {
            float s = 0.f;
#pragma unroll
            for (int r = 0; r < 4; ++r) {
                const float h = acc[mt][r] + bred[half][0][lane][mt * 4 + r]
                              + bred[half][1][lane][mt * 4 + r]
                              + bred[half][2][lane][mt * 4 + r];
                s = fmaf(bf2f(wv[mt * 4 + r]), h, s);
            }
            s += __shfl_xor(s, 1);    // reduce over d
            s += __shfl_xor(s, 2);
            s += __shfl_xor(s, 4);
            s += __shfl_xor(s, 16);   // reduce over t-quarters
            s += __shfl_xor(s, 32);
            part[mt] = s;
        }
        if (q == 0 && d == 0) {       // lanes 0 and 8: this half's 2 p's
            const int pl = col >> 3;
            float bv[N_];
#pragma unroll
            for (int mt = 0; mt < N_; ++mt) {
                bv[mt] = part[mt] * (1.0f / 512.0f);
                if (accum) bv[mt] += bbar[(size_t)p * N_ + mt];
                bbar[(size_t)p * N_ + mt] = bv[mt];
            }
            float m = -1e30f;
#pragma unroll
            for (int mt = 0; mt < N_; ++mt) m = fmaxf(m, bv[mt]);
            float sum = 0.f;
#pragma unroll
            for (int mt = 0; mt < N_; ++mt) { bv[mt] = __expf(bv[mt] - m); sum += bv[mt]; }
            const float inv = 1.f / sum;
#pragma unroll
            for (int mt = 0; mt < N_; ++mt) csm[half * 2 + pl][mt] = bv[mt] * inv;
        }
    }
    __syncthreads();
    const int p0 = blockIdx.x * 4;
#pragma unroll
    for (int task = tid; task < 640; task += 512) {   // Wc rebuild (4 p's)
        const int pl = task / 160, rem = task % 160;
        const int n = rem >> 4, cl = rem & 15;
        const int pp = p0 + pl;
        const float c = csm[pl][n];
        const float* wr = W + ((size_t)pp * NT_ + n * 16 + cl) * 8;
        const size_t addr = ((size_t)(n * NKC_ + (pp >> 2))) * 512 + (pp & 3) * 128 + cl * 8;
        *(bfrag*)(Wc + addr) = mkfrag(*(const f32x4*)wr, *(const f32x4*)(wr + 4), c);
    }
}

extern "C" void kernel_launch(void* const* d_in, const int* in_sizes, int n_in,
                              void* d_out, int out_size, void* d_ws, size_t ws_size,
                              hipStream_t stream) {
    const float* x = (const float*)d_in[0];   // fp32 [B][P*D]
    const float* W = (const float*)d_in[1];   // fp32 [P][NT][D]

    char* wsp = (char*)d_ws;
    float* bbar = (float*)wsp;                                      // 46080 B
    unsigned short* Xb  = (unsigned short*)(wsp + 46080);           // 9.44 MB
    unsigned short* Xga = Xb + (size_t)32 * NKC_ * 512;             // 9.44 MB
    unsigned short* Wc  = Xga + (size_t)576 * 16 * 512;             // 2.95 MB
    unsigned short* Wb  = Wc + (size_t)N_ * NKC_ * 512;             // 2.95 MB
    unsigned short* Vt  = Wb + (size_t)576 * 64 * 40;               // 160 KB
    float* outp = (float*)d_out;

    k_prep<<<dim3(2016), dim3(256), 0, stream>>>(x, W, Xb, Xga, Wc, Wb);
    k_sv<<<dim3(32, 5), dim3(1024), 0, stream>>>(Xb, Wc, Vt, outp, 0);
    k_ga<<<dim3(288), dim3(512), 0, stream>>>(Vt, Xga, Wb, W, bbar, Wc, 0);
    k_sv<<<dim3(32, 5), dim3(1024), 0, stream>>>(Xb, Wc, Vt, outp, 0);
    k_ga<<<dim3(288), dim3(512), 0, stream>>>(Vt, Xga, Wb, W, bbar, Wc, 1);
    k_sv<<<dim3(32, 5), dim3(1024), 0, stream>>>(Xb, Wc, Vt, outp, 1);
}

// Round 5
// 133.372 us; speedup vs baseline: 1.0957x; 1.0338x over previous
//
#include <hip/hip_runtime.h>
#include <hip/hip_bf16.h>

// CapsuleLayer routing, bf16 MFMA, 6 dispatches.
// B=512,P=1152,N=10,T=16,D=8, 3 iters. Verified 16x16x32 bf16 layouts:
//   A: m=lane&15, k=q*8+j   B: n=lane&15, k=q*8+j   D: col=lane&15, row=q*4+r
// r18 changes:
//  - k_sv: r17 XCD swizzle REVERTED (it broke the naturally-optimal mapping:
//    mblk = wg&31 with round-robin wg%8 already gives each XCD 4 mblk slices
//    {c,c+8,c+16,c+24} + whole Wc = 4.1MB ~ L2 size; r17 spread it to 5.8MB).
//  - k_ga: 288x2pdblk (2-round tail: 256+32 at 1 block/CU) -> 192x3pdblk,
//    768 thr, single round: wall 2.0*Tb -> 1.5*Tb; Vt traffic 46->31MB.
//  - k_prep: Wc0+Wb branches fused; W read ONCE coalesced into LDS (4 p-rows,
//    stride-9 pad), both outputs emitted from LDS. Fused blocks first so the
//    W stream overlaps the x-transpose HBM stream. Same emitted bytes.
// History: r15 traffic cut -18.6us (L2/L3-bound confirmed); r16 grid-halving
// REGRESSED +10us (coverage matters); r14 TLP/LDS-pad neutral; r11 grid-sync 4x.

typedef __attribute__((ext_vector_type(8))) short bfrag;   // 8 bf16
typedef __attribute__((ext_vector_type(4))) float f32x4;

constexpr int B_ = 512, P_ = 1152, N_ = 10, NT_ = 160;
constexpr int K1_ = 9216, NKC_ = 288;

__device__ __forceinline__ unsigned short f2bf(float f) {
    unsigned u = __float_as_uint(f);
    return (unsigned short)((u + 0x7fffu + ((u >> 16) & 1u)) >> 16);  // RNE
}
__device__ __forceinline__ float bf2f(unsigned short s) {
    return __uint_as_float((unsigned)s << 16);
}
__device__ __forceinline__ bfrag mkfrag(f32x4 a, f32x4 b, float c) {
    bfrag f;
    f[0] = (short)f2bf(a.x * c); f[1] = (short)f2bf(a.y * c);
    f[2] = (short)f2bf(a.z * c); f[3] = (short)f2bf(a.w * c);
    f[4] = (short)f2bf(b.x * c); f[5] = (short)f2bf(b.y * c);
    f[6] = (short)f2bf(b.z * c); f[7] = (short)f2bf(b.w * c);
    return f;
}

// Xb:  [mblk 32][kc 288][lane 64][8]  elem = x[mblk*16+col][kc*32+q*8+j]
// Xga: [pdblk 576][kc 16][lane 64][8] elem = x[kc*32+q*8+j][pdblk*16+col]
// Wc:  [n 10][kc 288][lane 64][8]     elem = c[p,n]*W[p][n*16+col][j], p=kc*4+q
// Wb:  [pdblk 576][lane 64][40]       elem(mt*4+r) = W[p][mt*16+q*4+r][d]
// Vt:  [kc 16][mt 10][lane 64][8]     elem = v[kc*32+q*8+j][mt*16+col]  (bf16)
__global__ __launch_bounds__(256) void k_prep(const float* __restrict__ x,
                                              const float* __restrict__ W,
                                              unsigned short* __restrict__ Xb,
                                              unsigned short* __restrict__ Xga,
                                              unsigned short* __restrict__ Wc,
                                              unsigned short* __restrict__ Wb) {
    __shared__ float smem[5760];   // 23 KB: fused-W stage OR x-transpose tile
    const int bid = blockIdx.x, tid = threadIdx.x;
    const int w = tid >> 6, ln = tid & 63, col = ln & 15, q = ln >> 4;
    if (bid < 288) {           // fused W branch: 4 p's per block, W read once
        const int pb = bid;            // == kc for Wc0
        const int p0 = pb * 4;
        // stage W[p0..p0+3] (5120 floats) coalesced -> LDS stride-9 pad
#pragma unroll
        for (int k = 0; k < 20; ++k) {
            const int e = k * 256 + tid;          // [0,5120)
            const int pl = e / 1280, rem = e % 1280;
            const int row = rem >> 3, d = rem & 7;
            smem[pl * 1440 + row * 9 + d] = W[(size_t)p0 * 1280 + e];
        }
        __syncthreads();
        // Wc0 = bf16(0.1*W): 10 (n) tasks over 4 waves; p = p0 + q
        for (int n = w; n < N_; n += 4) {
            const float* src = smem + q * 1440 + (n * 16 + col) * 9;
            bfrag f;
#pragma unroll
            for (int j = 0; j < 8; ++j) f[j] = (short)f2bf(src[j] * 0.1f);
            *(bfrag*)(Wc + ((size_t)(n * NKC_ + pb)) * 512 + ln * 8) = f;
        }
        // Wb: this block covers pdblk 2*pb + {0,1}; threads 0..127 emit
        if (tid < 128) {
            const int pdblk_l = tid >> 6;          // 0..1
            const int lane = tid & 63, c2 = lane & 15, q2 = lane >> 4;
            const int p_l = (pdblk_l * 16 + c2) >> 3, d = c2 & 7;
            const float* src = smem + p_l * 1440 + d;
            unsigned short* dst = Wb + ((size_t)((2 * pb + pdblk_l) * 64 + lane)) * 40;
#pragma unroll
            for (int mt = 0; mt < N_; ++mt)
#pragma unroll
                for (int r = 0; r < 4; ++r)
                    dst[mt * 4 + r] = f2bf(src[(mt * 16 + q2 * 4 + r) * 9]);
        }
    } else {                   // x transpose tile -> Xga AND Xb fragments
        unsigned short (*tile)[72] = (unsigned short (*)[72])smem;  // 64x72
        const int tb = bid - 288;
        const int pd0 = (tb >> 3) * 64, b0 = (tb & 7) * 64;
        const int c0 = tid & 63, r0 = tid >> 6;
#pragma unroll
        for (int i = 0; i < 16; ++i) {
            const int br = i * 4 + r0;   // coalesced: 64 lanes x 4B contiguous
            tile[c0][br] = f2bf(x[(size_t)(b0 + br) * K1_ + pd0 + c0]);
        }
        __syncthreads();
        // Xga: 8 frags (pdblk_l 0..3, kc_l 0..1); wave w does f=w, f=w+4
#pragma unroll
        for (int fi = 0; fi < 2; ++fi) {
            const int f = w + fi * 4;
            const int pdblk_l = f & 3, kc_l = f >> 2;
            bfrag fr;
#pragma unroll
            for (int j = 0; j < 8; ++j)
                fr[j] = (short)tile[pdblk_l * 16 + col][kc_l * 32 + q * 8 + j];
            const size_t addr = ((size_t)(((pd0 >> 4) + pdblk_l) * 16 + (b0 >> 5) + kc_l)) * 512 + ln * 8;
            *(bfrag*)(Xga + addr) = fr;   // 1KB/wave contiguous
        }
        // Xb: 8 frags (mblk_l 0..3, kc_l 0..1); wave w does f=w, f=w+4
#pragma unroll
        for (int fi = 0; fi < 2; ++fi) {
            const int f = w + fi * 4;
            const int mblk_l = f & 3, kc_l = f >> 2;
            bfrag fr;
#pragma unroll
            for (int j = 0; j < 8; ++j)
                fr[j] = (short)tile[kc_l * 32 + q * 8 + j][mblk_l * 16 + col];
            const size_t addr = ((size_t)(((b0 >> 4) + mblk_l) * NKC_ + (pd0 >> 5) + kc_l)) * 512 + ln * 8;
            *(bfrag*)(Xb + addr) = fr;    // 1KB/wave contiguous
        }
    }
}

// ---- GEMM1 + squash. grid (32,5), 1024 thr = 16 waves, 2 n's per block ----
// Natural mapping (mblk = blockIdx.x): each XCD's 20 blocks touch only 4 Xb
// slices + Wc (4.1MB ~ L2) under round-robin dispatch. Do not swizzle (r17).
__global__ __launch_bounds__(1024) void k_sv(const unsigned short* __restrict__ Xb,
                                             const unsigned short* __restrict__ Wc,
                                             unsigned short* __restrict__ Vt,
                                             float* __restrict__ outp,
                                             int final_it) {
    __shared__ float red[16][2][256];   // 32KB: all 16 waves x {n0,n1}
    const int tid = threadIdx.x;
    const int w = tid >> 6, lane = tid & 63, col = lane & 15, q = lane >> 4;
    const int mblk = blockIdx.x;        // 16 b-rows
    const int n0 = blockIdx.y * 2;      // two n per block

    f32x4 accA = (f32x4){0.f, 0.f, 0.f, 0.f};
    f32x4 accB = (f32x4){0.f, 0.f, 0.f, 0.f};
    const int kc0 = w * 18;             // 18 chunks per wave
    const unsigned short* Xp = Xb + ((size_t)(mblk * NKC_ + kc0)) * 512 + lane * 8;
    const unsigned short* W0 = Wc + ((size_t)(n0 * NKC_ + kc0)) * 512 + lane * 8;
    const unsigned short* W1 = W0 + (size_t)NKC_ * 512;
#pragma unroll 3
    for (int i = 0; i < 18; ++i) {
        const bfrag a  = *(const bfrag*)Xp;
        const bfrag b0 = *(const bfrag*)W0;
        const bfrag b1 = *(const bfrag*)W1;
        accA = __builtin_amdgcn_mfma_f32_16x16x32_bf16(a, b0, accA, 0, 0, 0);
        accB = __builtin_amdgcn_mfma_f32_16x16x32_bf16(a, b1, accB, 0, 0, 0);
        Xp += 512; W0 += 512; W1 += 512;
    }
#pragma unroll
    for (int r = 0; r < 4; ++r) {
        red[w][0][r * 64 + q * 16 + col] = accA[r];
        red[w][1][r * 64 + q * 16 + col] = accB[r];
    }
    __syncthreads();
    if (w < 2) {                        // wave 0 -> n0, wave 1 -> n0+1
        const int mt = n0 + w;
#pragma unroll
        for (int r = 0; r < 4; ++r) {
            const int li = r * 64 + q * 16 + col;
            float s = 0.f;
#pragma unroll
            for (int j = 0; j < 16; ++j) s += red[j][w][li];
            float sq = s * s;                      // t = col (16 lanes)
            sq += __shfl_xor(sq, 1);
            sq += __shfl_xor(sq, 2);
            sq += __shfl_xor(sq, 4);
            sq += __shfl_xor(sq, 8);
            const float norm = sqrtf(sq);
            const float scale = sq / (1.0f + sq * (norm + 1e-9f));
            const float vv = s * scale;
            const int b = mblk * 16 + q * 4 + r;
            if (final_it) {
                outp[(size_t)b * NT_ + mt * 16 + col] = vv;
            } else {
                const int b5 = b & 31;             // fragment layout write
                Vt[((size_t)((mblk >> 1) * N_ + mt)) * 512
                   + ((b5 >> 3) * 16 + col) * 8 + (b5 & 7)] = f2bf(vv);
            }
        }
    }
}

// ---- GEMM2 + contraction + softmax + Wc rebuild. grid 192, 768 thr -------
// Three pdblk per block: 192 <= 256 CUs -> SINGLE round (was 288 = 256+32
// two-round tail). Thirds share Vt frags via L1.
__global__ __launch_bounds__(768) void k_ga(const unsigned short* __restrict__ Vt,
                                            const unsigned short* __restrict__ Xga,
                                            const unsigned short* __restrict__ Wb,
                                            const float* __restrict__ W,
                                            float* __restrict__ bbar,
                                            unsigned short* __restrict__ Wc,
                                            int accum) {
    __shared__ float bred[3][3][64][41];   // 126KB; stride 41: conflict-free
    __shared__ float csm[6][N_];
    const int tid = threadIdx.x;
    const int w = tid >> 6, lane = tid & 63, col = lane & 15, q = lane >> 4;
    const int third = w >> 2, wl = w & 3;
    const int pdblk = blockIdx.x * 3 + third;
    const int p = (pdblk * 16 + col) >> 3, d = col & 7;

    f32x4 acc[N_];
#pragma unroll
    for (int mt = 0; mt < N_; ++mt) acc[mt] = (f32x4){0.f, 0.f, 0.f, 0.f};

    const int kb0 = wl * 4;
#pragma unroll
    for (int kc = kb0; kc < kb0 + 4; ++kc) {
        const bfrag bf = *(const bfrag*)(Xga + ((size_t)(pdblk * 16 + kc)) * 512 + lane * 8);
#pragma unroll
        for (int mt = 0; mt < N_; ++mt) {
            const bfrag af = *(const bfrag*)(Vt + ((size_t)(kc * N_ + mt)) * 512 + lane * 8);
            acc[mt] = __builtin_amdgcn_mfma_f32_16x16x32_bf16(af, bf, acc[mt], 0, 0, 0);
        }
    }
    if (wl) {
#pragma unroll
        for (int mt = 0; mt < N_; ++mt)
#pragma unroll
            for (int r = 0; r < 4; ++r)
                bred[third][wl - 1][lane][mt * 4 + r] = acc[mt][r];
    }
    __syncthreads();
    if (wl == 0) {
        unsigned short wv[40];
        const unsigned short* ws2 = Wb + ((size_t)(pdblk * 64 + lane)) * 40;
#pragma unroll
        for (int v = 0; v < 40; ++v) wv[v] = ws2[v];
        float part[N_];
#pragma unroll
        for (int mt = 0; mt < N_; ++mt) {
            float s = 0.f;
#pragma unroll
            for (int r = 0; r < 4; ++r) {
                const float h = acc[mt][r] + bred[third][0][lane][mt * 4 + r]
                              + bred[third][1][lane][mt * 4 + r]
                              + bred[third][2][lane][mt * 4 + r];
                s = fmaf(bf2f(wv[mt * 4 + r]), h, s);
            }
            s += __shfl_xor(s, 1);    // reduce over d
            s += __shfl_xor(s, 2);
            s += __shfl_xor(s, 4);
            s += __shfl_xor(s, 16);   // reduce over t-quarters
            s += __shfl_xor(s, 32);
            part[mt] = s;
        }
        if (q == 0 && d == 0) {       // lanes 0 and 8: this third's 2 p's
            const int pl = col >> 3;
            float bv[N_];
#pragma unroll
            for (int mt = 0; mt < N_; ++mt) {
                bv[mt] = part[mt] * (1.0f / 512.0f);
                if (accum) bv[mt] += bbar[(size_t)p * N_ + mt];
                bbar[(size_t)p * N_ + mt] = bv[mt];
            }
            float m = -1e30f;
#pragma unroll
            for (int mt = 0; mt < N_; ++mt) m = fmaxf(m, bv[mt]);
            float sum = 0.f;
#pragma unroll
            for (int mt = 0; mt < N_; ++mt) { bv[mt] = __expf(bv[mt] - m); sum += bv[mt]; }
            const float inv = 1.f / sum;
#pragma unroll
            for (int mt = 0; mt < N_; ++mt) csm[third * 2 + pl][mt] = bv[mt] * inv;
        }
    }
    __syncthreads();
    const int p0 = blockIdx.x * 6;
#pragma unroll
    for (int task = tid; task < 960; task += 768) {   // Wc rebuild (6 p's)
        const int pl = task / 160, rem = task % 160;
        const int n = rem >> 4, cl = rem & 15;
        const int pp = p0 + pl;
        const float c = csm[pl][n];
        const float* wr = W + ((size_t)pp * NT_ + n * 16 + cl) * 8;
        const size_t addr = ((size_t)(n * NKC_ + (pp >> 2))) * 512 + (pp & 3) * 128 + cl * 8;
        *(bfrag*)(Wc + addr) = mkfrag(*(const f32x4*)wr, *(const f32x4*)(wr + 4), c);
    }
}

extern "C" void kernel_launch(void* const* d_in, const int* in_sizes, int n_in,
                              void* d_out, int out_size, void* d_ws, size_t ws_size,
                              hipStream_t stream) {
    const float* x = (const float*)d_in[0];   // fp32 [B][P*D]
    const float* W = (const float*)d_in[1];   // fp32 [P][NT][D]

    char* wsp = (char*)d_ws;
    float* bbar = (float*)wsp;                                      // 46080 B
    unsigned short* Xb  = (unsigned short*)(wsp + 46080);           // 9.44 MB
    unsigned short* Xga = Xb + (size_t)32 * NKC_ * 512;             // 9.44 MB
    unsigned short* Wc  = Xga + (size_t)576 * 16 * 512;             // 2.95 MB
    unsigned short* Wb  = Wc + (size_t)N_ * NKC_ * 512;             // 2.95 MB
    unsigned short* Vt  = Wb + (size_t)576 * 64 * 40;               // 160 KB
    float* outp = (float*)d_out;

    k_prep<<<dim3(1440), dim3(256), 0, stream>>>(x, W, Xb, Xga, Wc, Wb);
    k_sv<<<dim3(32, 5), dim3(1024), 0, stream>>>(Xb, Wc, Vt, outp, 0);
    k_ga<<<dim3(192), dim3(768), 0, stream>>>(Vt, Xga, Wb, W, bbar, Wc, 0);
    k_sv<<<dim3(32, 5), dim3(1024), 0, stream>>>(Xb, Wc, Vt, outp, 0);
    k_ga<<<dim3(192), dim3(768), 0, stream>>>(Vt, Xga, Wb, W, bbar, Wc, 1);
    k_sv<<<dim3(32, 5), dim3(1024), 0, stream>>>(Xb, Wc, Vt, outp, 1);
}